// Round 1
// baseline (656.758 us; speedup 1.0000x reference)
//
#include <hip/hip_runtime.h>

typedef unsigned short u16;
typedef __attribute__((ext_vector_type(8))) short bh8;     // 8 bf16 (4 VGPRs) MFMA operand
typedef __attribute__((ext_vector_type(4))) float f32x4;   // MFMA accumulator
typedef __attribute__((ext_vector_type(4))) u16 us4;
typedef __attribute__((ext_vector_type(8))) u16 us8;

__device__ __forceinline__ u16 f2bf(float f){
  unsigned u = __builtin_bit_cast(unsigned, f);
  u += 0x7fffu + ((u >> 16) & 1u);           // RNE
  return (u16)(u >> 16);
}

__device__ __forceinline__ void gload16(const void* g, void* l){
  __builtin_amdgcn_global_load_lds((const __attribute__((address_space(1))) unsigned*)g,
                                   (__attribute__((address_space(3))) unsigned*)l, 16, 0, 0);
}

// ---------------------------------------------------------------------------
// Generic 128x128-tile bf16 GEMM core (m97 structure): A [M][K], B^T [N][K],
// BK=32, 256 threads = 4 waves, each wave a 64x64 sub-tile (4x4 frags 16x16x32).
// OUT_MODE: 0 = f32 out (+bias +resid), 1 = bf16 out (+bias), 2 = bf16 out
// transposed (out[col][row], +bias) for building V^T directly.
// ---------------------------------------------------------------------------
template<int OUT_MODE>
__device__ __forceinline__ void gemm_core(
    u16* As, u16* Bs,
    const u16* __restrict__ A, int lda,
    const u16* __restrict__ B, int ldb,
    int K, float scale,
    const float* __restrict__ bias,
    const float* __restrict__ resid, int ldr,
    float* __restrict__ outF, u16* __restrict__ outB, int ldo,
    int m0, int n0)
{
  const int t  = threadIdx.x;
  const int ln = t & 63;
  const int wv = t >> 6;
  const int wr = wv >> 1;
  const int wc = wv & 1;

  // staging: thread t loads 16B, rows t>>2, k-slot t&3; two rounds (rows 0-63, 64-127)
  const int rs = t >> 2;
  const int cs = (t & 3) * 8;
  const u16* Ag0 = A + (size_t)(m0 + rs) * lda + cs;
  const u16* Ag1 = Ag0 + (size_t)64 * lda;
  const u16* Bg0 = B + (size_t)(n0 + rs) * ldb + cs;
  const u16* Bg1 = Bg0 + (size_t)64 * ldb;
  // wave-uniform LDS dest bases (HW adds lane*16)
  char* lA0 = (char*)As + wv * 1024;
  char* lA1 = lA0 + 4096;
  char* lB0 = (char*)Bs + wv * 1024;
  char* lB1 = lB0 + 4096;

  f32x4 acc[4][4] = {};

  const int frow = (ln & 15);
  const int fk   = (ln >> 4) * 8;

  for (int k0 = 0; k0 < K; k0 += 32){
    gload16(Ag0 + k0, lA0);
    gload16(Ag1 + k0, lA1);
    gload16(Bg0 + k0, lB0);
    gload16(Bg1 + k0, lB1);
    __syncthreads();   // drains vmcnt before LDS reads
    bh8 a[4], b[4];
#pragma unroll
    for (int i = 0; i < 4; i++)
      a[i] = *(const bh8*)&As[(wr*64 + i*16 + frow)*32 + fk];
#pragma unroll
    for (int j = 0; j < 4; j++)
      b[j] = *(const bh8*)&Bs[(wc*64 + j*16 + frow)*32 + fk];
#pragma unroll
    for (int i = 0; i < 4; i++)
#pragma unroll
      for (int j = 0; j < 4; j++)
        acc[i][j] = __builtin_amdgcn_mfma_f32_16x16x32_bf16(a[i], b[j], acc[i][j], 0, 0, 0);
    __syncthreads();
  }

  // epilogue: C/D layout col = lane&15, row = (lane>>4)*4 + reg (m89-verified)
  const int col0 = ln & 15;
  const int r0   = (ln >> 4) * 4;
#pragma unroll
  for (int i = 0; i < 4; i++){
    const int rowb = m0 + wr*64 + i*16 + r0;
#pragma unroll
    for (int j = 0; j < 4; j++){
      const int col = n0 + wc*64 + j*16 + col0;
      f32x4 v = acc[i][j];
      const float bb = bias ? bias[col] : 0.f;
      if (OUT_MODE == 0){
#pragma unroll
        for (int q = 0; q < 4; q++){
          float o = v[q] * scale + bb;
          if (resid) o += resid[(size_t)(rowb + q) * ldr + col];
          outF[(size_t)(rowb + q) * ldo + col] = o;
        }
      } else if (OUT_MODE == 1){
#pragma unroll
        for (int q = 0; q < 4; q++)
          outB[(size_t)(rowb + q) * ldo + col] = f2bf(v[q] * scale + bb);
      } else {
        us4 pk;
#pragma unroll
        for (int q = 0; q < 4; q++) pk[q] = f2bf(v[q] * scale + bb);
        *(us4*)&outB[(size_t)col * ldo + rowb] = pk;   // rowb % 4 == 0 -> 8B aligned
      }
    }
  }
}

// ---------------------------- wrappers -------------------------------------

// Q/K projections: z = p*16 + bh (p in {0,1}), A = xb[b], B^T = WT[p*8+h]
__global__ __launch_bounds__(256) void k_qkv_qk(
    const u16* __restrict__ xb, const u16* __restrict__ WT,
    const float* __restrict__ bq, const float* __restrict__ bk,
    u16* __restrict__ Q, u16* __restrict__ Kb)
{
  __shared__ u16 As[4096], Bs[4096];
  const int z = blockIdx.z;
  const int p = z >> 4, bh = z & 15, b = bh >> 3, h = bh & 7;
  const u16* A = xb + (size_t)b * 2048 * 512;
  const u16* B = WT + (size_t)(p * 8 + h) * 512 * 512;
  const float* bias = (p == 0 ? bq : bk) + h * 512;
  u16* out = (p == 0 ? Q : Kb) + (size_t)bh * 2048 * 512;
  gemm_core<1>(As, Bs, A, 512, B, 512, 512, 1.f, bias, nullptr, 0,
               nullptr, out, 512, blockIdx.y * 128, blockIdx.x * 128);
}

// V projection with transposed output: VT[bh][e][s]
__global__ __launch_bounds__(256) void k_qkv_v(
    const u16* __restrict__ xb, const u16* __restrict__ WT,
    const float* __restrict__ bv, u16* __restrict__ VT)
{
  __shared__ u16 As[4096], Bs[4096];
  const int bh = blockIdx.z, b = bh >> 3, h = bh & 7;
  const u16* A = xb + (size_t)b * 2048 * 512;
  const u16* B = WT + (size_t)(16 + h) * 512 * 512;   // Wv block of WT
  gemm_core<2>(As, Bs, A, 512, B, 512, 512, 1.f, bv + h * 512, nullptr, 0,
               nullptr, VT + (size_t)bh * 512 * 2048, 2048,
               blockIdx.y * 128, blockIdx.x * 128);
}

// scores = scale * Q K^T  (f32), z = chunk-local bh
__global__ __launch_bounds__(256) void k_score(
    const u16* __restrict__ Q, const u16* __restrict__ Kb,
    float* __restrict__ scores, int bh0)
{
  __shared__ u16 As[4096], Bs[4096];
  const int z = blockIdx.z, bh = bh0 + z;
  gemm_core<0>(As, Bs, Q + (size_t)bh * 2048 * 512, 512,
               Kb + (size_t)bh * 2048 * 512, 512, 512,
               0.044194173824159216f /* 1/sqrt(512) */, nullptr, nullptr, 0,
               scores + (size_t)z * 2048 * 2048, nullptr, 2048,
               blockIdx.y * 128, blockIdx.x * 128);
}

// row softmax over 2048 f32, writes 2048 bf16 in place at row start
__global__ __launch_bounds__(256) void k_softmax(float* __restrict__ scores)
{
  float* row = scores + (size_t)blockIdx.x * 2048;
  const int t = threadIdx.x, ln = t & 63, wv = t >> 6;
  float4 v0 = *(const float4*)(row + t * 8);
  float4 v1 = *(const float4*)(row + t * 8 + 4);
  float vals[8] = {v0.x, v0.y, v0.z, v0.w, v1.x, v1.y, v1.z, v1.w};
  float m = vals[0];
#pragma unroll
  for (int q = 1; q < 8; q++) m = fmaxf(m, vals[q]);
#pragma unroll
  for (int off = 32; off; off >>= 1) m = fmaxf(m, __shfl_xor(m, off));
  __shared__ float redm[4], reds[4];
  if (ln == 0) redm[wv] = m;
  __syncthreads();
  m = fmaxf(fmaxf(redm[0], redm[1]), fmaxf(redm[2], redm[3]));
  float e[8], s = 0.f;
#pragma unroll
  for (int q = 0; q < 8; q++){ e[q] = __expf(vals[q] - m); s += e[q]; }
#pragma unroll
  for (int off = 32; off; off >>= 1) s += __shfl_xor(s, off);
  if (ln == 0) reds[wv] = s;
  __syncthreads();
  s = reds[0] + reds[1] + reds[2] + reds[3];
  const float inv = 1.f / s;
  us8 pk;
#pragma unroll
  for (int q = 0; q < 8; q++) pk[q] = f2bf(e[q] * inv);
  *(us8*)((u16*)row + t * 8) = pk;   // safe: all reads complete before barrier 1
}

// heads = P V, written into concat[b][s][h*512+e] (bf16). A = in-place bf16 P.
__global__ __launch_bounds__(256) void k_pv(
    const float* __restrict__ scores, const u16* __restrict__ VT,
    u16* __restrict__ concat, int bh0)
{
  __shared__ u16 As[4096], Bs[4096];
  const int z = blockIdx.z, bh = bh0 + z, b = bh >> 3, h = bh & 7;
  gemm_core<1>(As, Bs, (const u16*)(scores + (size_t)z * 2048 * 2048), 4096,
               VT + (size_t)bh * 512 * 2048, 2048, 2048, 1.f, nullptr, nullptr, 0,
               nullptr, concat + (size_t)b * 2048 * 4096 + h * 512, 4096,
               blockIdx.y * 128, blockIdx.x * 128);
}

// out = concat @ Wo + bo + x
__global__ __launch_bounds__(256) void k_final(
    const u16* __restrict__ concat, const u16* __restrict__ WoT,
    const float* __restrict__ bo, const float* __restrict__ x,
    float* __restrict__ out)
{
  __shared__ u16 As[4096], Bs[4096];
  gemm_core<0>(As, Bs, concat, 4096, WoT, 4096, 4096, 1.f, bo, x, 512,
               out, nullptr, 512, blockIdx.y * 128, blockIdx.x * 128);
}

// ------------------------- conversion kernels ------------------------------

__global__ void k_convx(const float* __restrict__ x, u16* __restrict__ xb)
{
  const int i = blockIdx.x * blockDim.x + threadIdx.x;
  float4 v = *(const float4*)(x + (size_t)i * 4);
  us4 o; o[0] = f2bf(v.x); o[1] = f2bf(v.y); o[2] = f2bf(v.z); o[3] = f2bf(v.w);
  *(us4*)(xb + (size_t)i * 4) = o;
}

// out[c][r] (bf16) = in[r][c] (f32); z-batched
__global__ void k_transpose_f2b(const float* __restrict__ in, u16* __restrict__ out,
                                int rows, int cols, size_t inStride, size_t outStride)
{
  __shared__ float tile[32][33];
  const float* ip = in + blockIdx.z * inStride;
  u16* op = out + blockIdx.z * outStride;
  const int c0 = blockIdx.x * 32, r0 = blockIdx.y * 32;
  const int tx = threadIdx.x, ty = threadIdx.y;
#pragma unroll
  for (int m = 0; m < 4; m++)
    tile[ty + m * 8][tx] = ip[(size_t)(r0 + ty + m * 8) * cols + c0 + tx];
  __syncthreads();
#pragma unroll
  for (int m = 0; m < 4; m++)
    op[(size_t)(c0 + ty + m * 8) * rows + r0 + tx] = f2bf(tile[tx][ty + m * 8]);
}

// ------------------------------ launcher -----------------------------------

extern "C" void kernel_launch(void* const* d_in, const int* in_sizes, int n_in,
                              void* d_out, int out_size, void* d_ws, size_t ws_size,
                              hipStream_t stream)
{
  const float* x  = (const float*)d_in[0];
  const float* Wq = (const float*)d_in[1];
  const float* Wk = (const float*)d_in[2];
  const float* Wv = (const float*)d_in[3];
  const float* bq = (const float*)d_in[4];
  const float* bk = (const float*)d_in[5];
  const float* bv = (const float*)d_in[6];
  const float* Wo = (const float*)d_in[7];
  const float* bo = (const float*)d_in[8];
  float* out = (float*)d_out;

  char* w = (char*)d_ws;
  size_t off = 0;
  auto alloc = [&](size_t bytes) -> char* {
    char* p = w + off; off += (bytes + 255) & ~(size_t)255; return p;
  };
  u16* xb   = (u16*)alloc(4096ull * 512 * 2);          //   4.2 MB
  u16* WT   = (u16*)alloc(3ull * 8 * 512 * 512 * 2);   //  12.6 MB  [p][h][e][d]
  u16* WoT  = (u16*)alloc(512ull * 4096 * 2);          //   4.2 MB  [e][i]
  u16* Q    = (u16*)alloc(16ull * 2048 * 512 * 2);     //  33.6 MB  [bh][s][e]
  u16* Kb   = (u16*)alloc(16ull * 2048 * 512 * 2);     //  33.6 MB  [bh][s][e]
  u16* VT   = (u16*)alloc(16ull * 512 * 2048 * 2);     //  33.6 MB  [bh][e][s]
  u16* conc = (u16*)alloc(4096ull * 4096 * 2);         //  33.6 MB  [b*s][h*e]
  const size_t scoreBytes = 2048ull * 2048 * 4;        //  16.8 MB per bh
  int CH = 4;
  while (CH > 1 && off + (size_t)CH * scoreBytes > ws_size) CH >>= 1;
  float* scores = (float*)alloc((size_t)CH * scoreBytes);

  // 1) converts / transposes
  k_convx<<<2048, 256, 0, stream>>>(x, xb);
  dim3 tb(32, 8);
  k_transpose_f2b<<<dim3(16, 16, 8), tb, 0, stream>>>(Wq, WT + 0ull * 2097152, 512, 512, 262144, 262144);
  k_transpose_f2b<<<dim3(16, 16, 8), tb, 0, stream>>>(Wk, WT + 1ull * 2097152, 512, 512, 262144, 262144);
  k_transpose_f2b<<<dim3(16, 16, 8), tb, 0, stream>>>(Wv, WT + 2ull * 2097152, 512, 512, 262144, 262144);
  k_transpose_f2b<<<dim3(16, 128, 1), tb, 0, stream>>>(Wo, WoT, 4096, 512, 0, 0);

  // 2) QKV projections
  k_qkv_qk<<<dim3(4, 16, 32), 256, 0, stream>>>(xb, WT, bq, bk, Q, Kb);
  k_qkv_v <<<dim3(4, 16, 16), 256, 0, stream>>>(xb, WT, bv, VT);

  // 3) attention, chunked over (b,h)
  for (int c = 0; c < 16; c += CH){
    k_score  <<<dim3(16, 16, CH), 256, 0, stream>>>(Q, Kb, scores, c);
    k_softmax<<<dim3(CH * 2048), 256, 0, stream>>>(scores);
    k_pv     <<<dim3(4, 16, CH), 256, 0, stream>>>(scores, VT, conc, c);
  }

  // 4) output projection + bias + residual
  k_final<<<dim3(4, 32), 256, 0, stream>>>(conc, WoT, bo, x, out);
}

// Round 3
// 494.725 us; speedup vs baseline: 1.3275x; 1.3275x over previous
//
#include <hip/hip_runtime.h>

typedef unsigned short u16;
typedef __attribute__((ext_vector_type(8))) short bh8;     // 8 bf16 (4 VGPRs) MFMA operand
typedef __attribute__((ext_vector_type(4))) float f32x4;   // MFMA accumulator
typedef __attribute__((ext_vector_type(4))) u16 us4;
typedef __attribute__((ext_vector_type(8))) u16 us8;

__device__ __forceinline__ u16 f2bf(float f){
  unsigned u = __builtin_bit_cast(unsigned, f);
  u += 0x7fffu + ((u >> 16) & 1u);           // RNE
  return (u16)(u >> 16);
}
__device__ __forceinline__ float bf2f(u16 b){
  unsigned u = ((unsigned)b) << 16;
  return __builtin_bit_cast(float, u);
}

__device__ __forceinline__ void gload16(const void* g, void* l){
  __builtin_amdgcn_global_load_lds((const __attribute__((address_space(1))) unsigned*)g,
                                   (__attribute__((address_space(3))) unsigned*)l, 16, 0, 0);
}

// ---------------------------------------------------------------------------
// Generic 128x128-tile bf16 GEMM core (m97 structure): A [M][K], B^T [N][K],
// BK=32, 256 threads = 4 waves, each wave a 64x64 sub-tile (4x4 frags 16x16x32).
// OUT_MODE: 0 = f32 out (+bias +resid), 1 = bf16 out (+bias), 2 = bf16 out
// transposed (out[col][row], +bias) for building V^T directly.
// ---------------------------------------------------------------------------
template<int OUT_MODE>
__device__ __forceinline__ void gemm_core(
    u16* As, u16* Bs,
    const u16* __restrict__ A, int lda,
    const u16* __restrict__ B, int ldb,
    int K, float scale,
    const float* __restrict__ bias,
    const float* __restrict__ resid, int ldr,
    float* __restrict__ outF, u16* __restrict__ outB, int ldo,
    int m0, int n0)
{
  const int t  = threadIdx.x;
  const int ln = t & 63;
  const int wv = t >> 6;
  const int wr = wv >> 1;
  const int wc = wv & 1;

  // staging: thread t loads 16B, rows t>>2, k-slot t&3; two rounds (rows 0-63, 64-127)
  const int rs = t >> 2;
  const int cs = (t & 3) * 8;
  const u16* Ag0 = A + (size_t)(m0 + rs) * lda + cs;
  const u16* Ag1 = Ag0 + (size_t)64 * lda;
  const u16* Bg0 = B + (size_t)(n0 + rs) * ldb + cs;
  const u16* Bg1 = Bg0 + (size_t)64 * ldb;
  // wave-uniform LDS dest bases (HW adds lane*16)
  char* lA0 = (char*)As + wv * 1024;
  char* lA1 = lA0 + 4096;
  char* lB0 = (char*)Bs + wv * 1024;
  char* lB1 = lB0 + 4096;

  f32x4 acc[4][4] = {};

  const int frow = (ln & 15);
  const int fk   = (ln >> 4) * 8;

  for (int k0 = 0; k0 < K; k0 += 32){
    gload16(Ag0 + k0, lA0);
    gload16(Ag1 + k0, lA1);
    gload16(Bg0 + k0, lB0);
    gload16(Bg1 + k0, lB1);
    __syncthreads();   // drains vmcnt before LDS reads
    bh8 a[4], b[4];
#pragma unroll
    for (int i = 0; i < 4; i++)
      a[i] = *(const bh8*)&As[(wr*64 + i*16 + frow)*32 + fk];
#pragma unroll
    for (int j = 0; j < 4; j++)
      b[j] = *(const bh8*)&Bs[(wc*64 + j*16 + frow)*32 + fk];
#pragma unroll
    for (int i = 0; i < 4; i++)
#pragma unroll
      for (int j = 0; j < 4; j++)
        acc[i][j] = __builtin_amdgcn_mfma_f32_16x16x32_bf16(a[i], b[j], acc[i][j], 0, 0, 0);
    __syncthreads();
  }

  // epilogue: C/D layout col = lane&15, row = (lane>>4)*4 + reg (m89-verified)
  const int col0 = ln & 15;
  const int r0   = (ln >> 4) * 4;
#pragma unroll
  for (int i = 0; i < 4; i++){
    const int rowb = m0 + wr*64 + i*16 + r0;
#pragma unroll
    for (int j = 0; j < 4; j++){
      const int col = n0 + wc*64 + j*16 + col0;
      f32x4 v = acc[i][j];
      const float bb = bias ? bias[col] : 0.f;
      if (OUT_MODE == 0){
#pragma unroll
        for (int q = 0; q < 4; q++){
          float o = v[q] * scale + bb;
          if (resid) o += resid[(size_t)(rowb + q) * ldr + col];
          outF[(size_t)(rowb + q) * ldo + col] = o;
        }
      } else if (OUT_MODE == 1){
#pragma unroll
        for (int q = 0; q < 4; q++)
          outB[(size_t)(rowb + q) * ldo + col] = f2bf(v[q] * scale + bb);
      } else {
        us4 pk;
#pragma unroll
        for (int q = 0; q < 4; q++) pk[q] = f2bf(v[q] * scale + bb);
        *(us4*)&outB[(size_t)col * ldo + rowb] = pk;   // rowb % 4 == 0 -> 8B aligned
      }
    }
  }
}

// ---------------------------- wrappers -------------------------------------

// Q/K projections: z = p*16 + bh (p in {0,1}), A = xb[b], B^T = WT[p*8+h]
__global__ __launch_bounds__(256) void k_qkv_qk(
    const u16* __restrict__ xb, const u16* __restrict__ WT,
    const float* __restrict__ bq, const float* __restrict__ bk,
    u16* __restrict__ Q, u16* __restrict__ Kb)
{
  __shared__ u16 As[4096], Bs[4096];
  const int z = blockIdx.z;
  const int p = z >> 4, bh = z & 15, b = bh >> 3, h = bh & 7;
  const u16* A = xb + (size_t)b * 2048 * 512;
  const u16* B = WT + (size_t)(p * 8 + h) * 512 * 512;
  const float* bias = (p == 0 ? bq : bk) + h * 512;
  u16* out = (p == 0 ? Q : Kb) + (size_t)bh * 2048 * 512;
  gemm_core<1>(As, Bs, A, 512, B, 512, 512, 1.f, bias, nullptr, 0,
               nullptr, out, 512, blockIdx.y * 128, blockIdx.x * 128);
}

// V projection with transposed output: VT[bh][e][s]
__global__ __launch_bounds__(256) void k_qkv_v(
    const u16* __restrict__ xb, const u16* __restrict__ WT,
    const float* __restrict__ bv, u16* __restrict__ VT)
{
  __shared__ u16 As[4096], Bs[4096];
  const int bh = blockIdx.z, b = bh >> 3, h = bh & 7;
  const u16* A = xb + (size_t)b * 2048 * 512;
  const u16* B = WT + (size_t)(16 + h) * 512 * 512;   // Wv block of WT
  gemm_core<2>(As, Bs, A, 512, B, 512, 512, 1.f, bv + h * 512, nullptr, 0,
               nullptr, VT + (size_t)bh * 512 * 2048, 2048,
               blockIdx.y * 128, blockIdx.x * 128);
}

// scores = scale * Q K^T  -> bf16, z = chunk-local bh
__global__ __launch_bounds__(256) void k_score(
    const u16* __restrict__ Q, const u16* __restrict__ Kb,
    u16* __restrict__ scoresB, int bh0)
{
  __shared__ u16 As[4096], Bs[4096];
  const int z = blockIdx.z, bh = bh0 + z;
  gemm_core<1>(As, Bs, Q + (size_t)bh * 2048 * 512, 512,
               Kb + (size_t)bh * 2048 * 512, 512, 512,
               0.044194173824159216f /* 1/sqrt(512) */, nullptr, nullptr, 0,
               nullptr, scoresB + (size_t)z * 2048 * 2048, 2048,
               blockIdx.y * 128, blockIdx.x * 128);
}

// row softmax over 2048 bf16 scores, writes 2048 bf16 P in place
__global__ __launch_bounds__(256) void k_softmax(u16* __restrict__ scoresB)
{
  u16* row = scoresB + (size_t)blockIdx.x * 2048;
  const int t = threadIdx.x, ln = t & 63, wv = t >> 6;
  us8 in = *(const us8*)(row + t * 8);
  float vals[8];
#pragma unroll
  for (int q = 0; q < 8; q++) vals[q] = bf2f(in[q]);
  float m = vals[0];
#pragma unroll
  for (int q = 1; q < 8; q++) m = fmaxf(m, vals[q]);
#pragma unroll
  for (int off = 32; off; off >>= 1) m = fmaxf(m, __shfl_xor(m, off));
  __shared__ float redm[4], reds[4];
  if (ln == 0) redm[wv] = m;
  __syncthreads();
  m = fmaxf(fmaxf(redm[0], redm[1]), fmaxf(redm[2], redm[3]));
  float e[8], s = 0.f;
#pragma unroll
  for (int q = 0; q < 8; q++){ e[q] = __expf(vals[q] - m); s += e[q]; }
#pragma unroll
  for (int off = 32; off; off >>= 1) s += __shfl_xor(s, off);
  if (ln == 0) reds[wv] = s;
  __syncthreads();
  s = reds[0] + reds[1] + reds[2] + reds[3];
  const float inv = 1.f / s;
  us8 pk;
#pragma unroll
  for (int q = 0; q < 8; q++) pk[q] = f2bf(e[q] * inv);
  *(us8*)(row + t * 8) = pk;   // each thread reads/writes only its own 8 elems
}

// heads = P V, written into concat[b][s][h*512+e] (bf16). A = bf16 P.
__global__ __launch_bounds__(256) void k_pv(
    const u16* __restrict__ scoresB, const u16* __restrict__ VT,
    u16* __restrict__ concat, int bh0)
{
  __shared__ u16 As[4096], Bs[4096];
  const int z = blockIdx.z, bh = bh0 + z, b = bh >> 3, h = bh & 7;
  gemm_core<1>(As, Bs, scoresB + (size_t)z * 2048 * 2048, 2048,
               VT + (size_t)bh * 512 * 2048, 2048, 2048, 1.f, nullptr, nullptr, 0,
               nullptr, concat + (size_t)b * 2048 * 4096 + h * 512, 4096,
               blockIdx.y * 128, blockIdx.x * 128);
}

// out-proj partials: partial[sk] = concat[:, sk*1024:(sk+1)*1024] @ WoT_slice
__global__ __launch_bounds__(256) void k_final_sk(
    const u16* __restrict__ concat, const u16* __restrict__ WoT,
    float* __restrict__ partial)
{
  __shared__ u16 As[4096], Bs[4096];
  const int sk = blockIdx.z;
  gemm_core<0>(As, Bs, concat + sk * 1024, 4096,
               WoT + sk * 1024, 4096, 1024, 1.f, nullptr, nullptr, 0,
               partial + (size_t)sk * 4096 * 512, nullptr, 512,
               blockIdx.y * 128, blockIdx.x * 128);
}

// out = sum_sk partial[sk] + bo + x   (vectorized x4)
__global__ __launch_bounds__(256) void k_reduce(
    const float* __restrict__ partial, const float* __restrict__ bo,
    const float* __restrict__ x, float* __restrict__ out)
{
  const size_t i4 = ((size_t)blockIdx.x * 256 + threadIdx.x) * 4;  // 2M elems
  const int col = (int)(i4 & 511);
  float4 s = *(const float4*)(x + i4);
  s.x += bo[col]; s.y += bo[col + 1]; s.z += bo[col + 2]; s.w += bo[col + 3];
#pragma unroll
  for (int sk = 0; sk < 4; sk++){
    float4 p = *(const float4*)(partial + (size_t)sk * 2097152 + i4);
    s.x += p.x; s.y += p.y; s.z += p.z; s.w += p.w;
  }
  *(float4*)(out + i4) = s;
}

// ------------------------- conversion kernels ------------------------------

__global__ void k_convx(const float* __restrict__ x, u16* __restrict__ xb)
{
  const int i = blockIdx.x * blockDim.x + threadIdx.x;
  float4 v = *(const float4*)(x + (size_t)i * 4);
  us4 o; o[0] = f2bf(v.x); o[1] = f2bf(v.y); o[2] = f2bf(v.z); o[3] = f2bf(v.w);
  *(us4*)(xb + (size_t)i * 4) = o;
}

// out[c][r] (bf16) = in[r][c] (f32); z-batched
__global__ void k_transpose_f2b(const float* __restrict__ in, u16* __restrict__ out,
                                int rows, int cols, size_t inStride, size_t outStride)
{
  __shared__ float tile[32][33];
  const float* ip = in + blockIdx.z * inStride;
  u16* op = out + blockIdx.z * outStride;
  const int c0 = blockIdx.x * 32, r0 = blockIdx.y * 32;
  const int tx = threadIdx.x, ty = threadIdx.y;
#pragma unroll
  for (int m = 0; m < 4; m++)
    tile[ty + m * 8][tx] = ip[(size_t)(r0 + ty + m * 8) * cols + c0 + tx];
  __syncthreads();
#pragma unroll
  for (int m = 0; m < 4; m++)
    op[(size_t)(c0 + ty + m * 8) * rows + r0 + tx] = f2bf(tile[tx][ty + m * 8]);
}

// ------------------------------ launcher -----------------------------------

extern "C" void kernel_launch(void* const* d_in, const int* in_sizes, int n_in,
                              void* d_out, int out_size, void* d_ws, size_t ws_size,
                              hipStream_t stream)
{
  const float* x  = (const float*)d_in[0];
  const float* Wq = (const float*)d_in[1];
  const float* Wk = (const float*)d_in[2];
  const float* Wv = (const float*)d_in[3];
  const float* bq = (const float*)d_in[4];
  const float* bk = (const float*)d_in[5];
  const float* bv = (const float*)d_in[6];
  const float* Wo = (const float*)d_in[7];
  const float* bo = (const float*)d_in[8];
  float* out = (float*)d_out;

  char* w = (char*)d_ws;
  size_t off = 0;
  auto alloc = [&](size_t bytes) -> char* {
    char* p = w + off; off += (bytes + 255) & ~(size_t)255; return p;
  };
  u16* xb   = (u16*)alloc(4096ull * 512 * 2);          //   4.2 MB
  u16* WT   = (u16*)alloc(3ull * 8 * 512 * 512 * 2);   //  12.6 MB  [p][h][e][d]
  u16* WoT  = (u16*)alloc(512ull * 4096 * 2);          //   4.2 MB  [e][i]
  u16* Q    = (u16*)alloc(16ull * 2048 * 512 * 2);     //  33.6 MB  [bh][s][e]
  u16* Kb   = (u16*)alloc(16ull * 2048 * 512 * 2);     //  33.6 MB  [bh][s][e]
  u16* VT   = (u16*)alloc(16ull * 512 * 2048 * 2);     //  33.6 MB  [bh][e][s]
  u16* conc = (u16*)alloc(4096ull * 4096 * 2);         //  33.6 MB  [b*s][h*e]
  float* part = (float*)alloc(4ull * 4096 * 512 * 4);  //  33.6 MB  split-K partials
  const size_t scoreBytes = 2048ull * 2048 * 2;        //   8.4 MB per bh (bf16)
  int CH = 16;
  while (CH > 1 && off + (size_t)CH * scoreBytes > ws_size) CH >>= 1;
  u16* scores = (u16*)alloc((size_t)CH * scoreBytes);

  // 1) converts / transposes
  k_convx<<<2048, 256, 0, stream>>>(x, xb);
  dim3 tb(32, 8);
  k_transpose_f2b<<<dim3(16, 16, 8), tb, 0, stream>>>(Wq, WT + 0ull * 2097152, 512, 512, 262144, 262144);
  k_transpose_f2b<<<dim3(16, 16, 8), tb, 0, stream>>>(Wk, WT + 1ull * 2097152, 512, 512, 262144, 262144);
  k_transpose_f2b<<<dim3(16, 16, 8), tb, 0, stream>>>(Wv, WT + 2ull * 2097152, 512, 512, 262144, 262144);
  k_transpose_f2b<<<dim3(16, 128, 1), tb, 0, stream>>>(Wo, WoT, 4096, 512, 0, 0);

  // 2) QKV projections
  k_qkv_qk<<<dim3(4, 16, 32), 256, 0, stream>>>(xb, WT, bq, bk, Q, Kb);
  k_qkv_v <<<dim3(4, 16, 16), 256, 0, stream>>>(xb, WT, bv, VT);

  // 3) attention, chunked over (b,h)
  for (int c = 0; c < 16; c += CH){
    k_score  <<<dim3(16, 16, CH), 256, 0, stream>>>(Q, Kb, scores, c);
    k_softmax<<<dim3(CH * 2048), 256, 0, stream>>>(scores);
    k_pv     <<<dim3(4, 16, CH), 256, 0, stream>>>(scores, VT, conc, c);
  }

  // 4) output projection (split-K=4) + reduce(+bias+residual)
  k_final_sk<<<dim3(4, 32, 4), 256, 0, stream>>>(conc, WoT, part);
  k_reduce<<<2048, 256, 0, stream>>>(part, bo, x, out);
}

// Round 4
// 465.587 us; speedup vs baseline: 1.4106x; 1.0626x over previous
//
#include <hip/hip_runtime.h>

typedef unsigned short u16;
typedef __attribute__((ext_vector_type(8))) short bh8;     // 8 bf16 (4 VGPRs) MFMA operand
typedef __attribute__((ext_vector_type(4))) float f32x4;   // MFMA accumulator
typedef __attribute__((ext_vector_type(4))) u16 us4;
typedef __attribute__((ext_vector_type(8))) u16 us8;

__device__ __forceinline__ u16 f2bf(float f){
  unsigned u = __builtin_bit_cast(unsigned, f);
  u += 0x7fffu + ((u >> 16) & 1u);           // RNE
  return (u16)(u >> 16);
}
__device__ __forceinline__ float bf2f(u16 b){
  unsigned u = ((unsigned)b) << 16;
  return __builtin_bit_cast(float, u);
}

__device__ __forceinline__ void gload16(const void* g, void* l){
  __builtin_amdgcn_global_load_lds((const __attribute__((address_space(1))) unsigned*)g,
                                   (__attribute__((address_space(3))) unsigned*)l, 16, 0, 0);
}

// ---------------------------------------------------------------------------
// Generic 128x128-tile bf16 GEMM core (m97 structure): A [M][K], B^T [N][K],
// BK=32, 256 threads = 4 waves, each wave a 64x64 sub-tile (4x4 frags 16x16x32).
// OUT_MODE: 1 = bf16 out (+bias); 2 = bf16 out transposed (V^T build);
//           3 = bf16 exp(v*scale) + per-row sum atomics into lsum;
//           4 = bf16 v * (1/linv_raw[row])  (PV normalize-in-epilogue).
// ---------------------------------------------------------------------------
template<int OUT_MODE>
__device__ __forceinline__ void gemm_core(
    u16* As, u16* Bs,
    const u16* __restrict__ A, int lda,
    const u16* __restrict__ B, int ldb,
    int K, float scale,
    const float* __restrict__ bias,
    float* __restrict__ lsum,          // mode 3: row-sum atomics base (global rows)
    const float* __restrict__ lraw,    // mode 4: row sums base (global rows)
    u16* __restrict__ outB, int ldo,
    int m0, int n0)
{
  const int t  = threadIdx.x;
  const int ln = t & 63;
  const int wv = t >> 6;
  const int wr = wv >> 1;
  const int wc = wv & 1;

  // staging: thread t loads 16B, rows t>>2, k-slot t&3; two rounds (rows 0-63, 64-127)
  const int rs = t >> 2;
  const int cs = (t & 3) * 8;
  const u16* Ag0 = A + (size_t)(m0 + rs) * lda + cs;
  const u16* Ag1 = Ag0 + (size_t)64 * lda;
  const u16* Bg0 = B + (size_t)(n0 + rs) * ldb + cs;
  const u16* Bg1 = Bg0 + (size_t)64 * ldb;
  // wave-uniform LDS dest bases (HW adds lane*16)
  char* lA0 = (char*)As + wv * 1024;
  char* lA1 = lA0 + 4096;
  char* lB0 = (char*)Bs + wv * 1024;
  char* lB1 = lB0 + 4096;

  f32x4 acc[4][4] = {};

  const int frow = (ln & 15);
  const int fk   = (ln >> 4) * 8;

  for (int k0 = 0; k0 < K; k0 += 32){
    gload16(Ag0 + k0, lA0);
    gload16(Ag1 + k0, lA1);
    gload16(Bg0 + k0, lB0);
    gload16(Bg1 + k0, lB1);
    __syncthreads();   // drains vmcnt before LDS reads
    bh8 a[4], b[4];
#pragma unroll
    for (int i = 0; i < 4; i++)
      a[i] = *(const bh8*)&As[(wr*64 + i*16 + frow)*32 + fk];
#pragma unroll
    for (int j = 0; j < 4; j++)
      b[j] = *(const bh8*)&Bs[(wc*64 + j*16 + frow)*32 + fk];
#pragma unroll
    for (int i = 0; i < 4; i++)
#pragma unroll
      for (int j = 0; j < 4; j++)
        acc[i][j] = __builtin_amdgcn_mfma_f32_16x16x32_bf16(a[i], b[j], acc[i][j], 0, 0, 0);
    __syncthreads();
  }

  // epilogue: C/D layout col = lane&15, row = (lane>>4)*4 + reg (m89-verified)
  const int col0 = ln & 15;
  const int r0   = (ln >> 4) * 4;
  float rsum[4][4];   // mode 3: per-(i,q) row partial over this thread's 4 j-cols
#pragma unroll
  for (int i = 0; i < 4; i++){
    const int rowb = m0 + wr*64 + i*16 + r0;
#pragma unroll
    for (int q = 0; q < 4; q++) rsum[i][q] = 0.f;
#pragma unroll
    for (int j = 0; j < 4; j++){
      const int col = n0 + wc*64 + j*16 + col0;
      f32x4 v = acc[i][j];
      if (OUT_MODE == 1){
        const float bb = bias ? bias[col] : 0.f;
#pragma unroll
        for (int q = 0; q < 4; q++)
          outB[(size_t)(rowb + q) * ldo + col] = f2bf(v[q] * scale + bb);
      } else if (OUT_MODE == 2){
        const float bb = bias ? bias[col] : 0.f;
        us4 pk;
#pragma unroll
        for (int q = 0; q < 4; q++) pk[q] = f2bf(v[q] * scale + bb);
        *(us4*)&outB[(size_t)col * ldo + rowb] = pk;   // rowb % 4 == 0 -> 8B aligned
      } else if (OUT_MODE == 3){
#pragma unroll
        for (int q = 0; q < 4; q++){
          float e = __expf(v[q] * scale);
          rsum[i][q] += e;
          outB[(size_t)(rowb + q) * ldo + col] = f2bf(e);
        }
      } else { // 4
#pragma unroll
        for (int q = 0; q < 4; q++){
          float il = 1.0f / lraw[rowb + q];
          outB[(size_t)(rowb + q) * ldo + col] = f2bf(v[q] * il);
        }
      }
    }
    if (OUT_MODE == 3){
      // reduce rsum over the 16 col-lanes (ln&15), then 1 atomic per row
#pragma unroll
      for (int q = 0; q < 4; q++){
        float s = rsum[i][q];
        s += __shfl_xor(s, 1);
        s += __shfl_xor(s, 2);
        s += __shfl_xor(s, 4);
        s += __shfl_xor(s, 8);
        if ((ln & 15) == 0) atomicAdd(&lsum[rowb + q], s);
      }
    }
  }
}

// ---------------------------- wrappers -------------------------------------

// Q/K projections: z = p*16 + bh (p in {0,1}), A = xb[b], B^T = WT[p*8+h]
__global__ __launch_bounds__(256) void k_qkv_qk(
    const u16* __restrict__ xb, const u16* __restrict__ WT,
    const float* __restrict__ bq, const float* __restrict__ bk,
    u16* __restrict__ Q, u16* __restrict__ Kb)
{
  __shared__ u16 As[4096], Bs[4096];
  const int z = blockIdx.z;
  const int p = z >> 4, bh = z & 15, b = bh >> 3, h = bh & 7;
  const u16* A = xb + (size_t)b * 2048 * 512;
  const u16* B = WT + (size_t)(p * 8 + h) * 512 * 512;
  const float* bias = (p == 0 ? bq : bk) + h * 512;
  u16* out = (p == 0 ? Q : Kb) + (size_t)bh * 2048 * 512;
  gemm_core<1>(As, Bs, A, 512, B, 512, 512, 1.f, bias, nullptr, nullptr,
               out, 512, blockIdx.y * 128, blockIdx.x * 128);
}

// V projection with transposed output: VT[bh][e][s]
__global__ __launch_bounds__(256) void k_qkv_v(
    const u16* __restrict__ xb, const u16* __restrict__ WT,
    const float* __restrict__ bv, u16* __restrict__ VT)
{
  __shared__ u16 As[4096], Bs[4096];
  const int bh = blockIdx.z, b = bh >> 3, h = bh & 7;
  const u16* A = xb + (size_t)b * 2048 * 512;
  const u16* B = WT + (size_t)(16 + h) * 512 * 512;   // Wv block of WT
  gemm_core<2>(As, Bs, A, 512, B, 512, 512, 1.f, bv + h * 512, nullptr, nullptr,
               VT + (size_t)bh * 512 * 2048, 2048,
               blockIdx.y * 128, blockIdx.x * 128);
}

// P_unnorm = exp(scale * Q K^T)  -> bf16, plus row-sum atomics into l
__global__ __launch_bounds__(256) void k_score(
    const u16* __restrict__ Q, const u16* __restrict__ Kb,
    u16* __restrict__ scoresB, float* __restrict__ l, int bh0)
{
  __shared__ u16 As[4096], Bs[4096];
  const int z = blockIdx.z, bh = bh0 + z;
  gemm_core<3>(As, Bs, Q + (size_t)bh * 2048 * 512, 512,
               Kb + (size_t)bh * 2048 * 512, 512, 512,
               0.044194173824159216f /* 1/sqrt(512) */, nullptr,
               l + (size_t)bh * 2048, nullptr,
               scoresB + (size_t)z * 2048 * 2048, 2048,
               blockIdx.y * 128, blockIdx.x * 128);
}

// heads = (P_unnorm V) / l, written into concat[b][s][h*512+e] (bf16)
__global__ __launch_bounds__(256) void k_pv(
    const u16* __restrict__ scoresB, const u16* __restrict__ VT,
    const float* __restrict__ l, u16* __restrict__ concat, int bh0)
{
  __shared__ u16 As[4096], Bs[4096];
  const int z = blockIdx.z, bh = bh0 + z, b = bh >> 3, h = bh & 7;
  gemm_core<4>(As, Bs, scoresB + (size_t)z * 2048 * 2048, 2048,
               VT + (size_t)bh * 512 * 2048, 2048, 2048, 1.f, nullptr,
               nullptr, l + (size_t)bh * 2048,
               concat + (size_t)b * 2048 * 4096 + h * 512, 4096,
               blockIdx.y * 128, blockIdx.x * 128);
}

// out-proj partials (bf16): partial[sk] = concat[:, sk*1024:(sk+1)*1024] @ WoT_slice
__global__ __launch_bounds__(256) void k_final_sk(
    const u16* __restrict__ concat, const u16* __restrict__ WoT,
    u16* __restrict__ partialB)
{
  __shared__ u16 As[4096], Bs[4096];
  const int sk = blockIdx.z;
  gemm_core<1>(As, Bs, concat + sk * 1024, 4096,
               WoT + sk * 1024, 4096, 1024, 1.f, nullptr, nullptr, nullptr,
               partialB + (size_t)sk * 4096 * 512, 512,
               blockIdx.y * 128, blockIdx.x * 128);
}

// out = sum_sk partial[sk] + bo + x   (vectorized x4)
__global__ __launch_bounds__(256) void k_reduce(
    const u16* __restrict__ partialB, const float* __restrict__ bo,
    const float* __restrict__ x, float* __restrict__ out)
{
  const size_t i4 = ((size_t)blockIdx.x * 256 + threadIdx.x) * 4;  // 2M elems
  const int col = (int)(i4 & 511);
  float4 s = *(const float4*)(x + i4);
  s.x += bo[col]; s.y += bo[col + 1]; s.z += bo[col + 2]; s.w += bo[col + 3];
#pragma unroll
  for (int sk = 0; sk < 4; sk++){
    us4 p = *(const us4*)(partialB + (size_t)sk * 2097152 + i4);
    s.x += bf2f(p[0]); s.y += bf2f(p[1]); s.z += bf2f(p[2]); s.w += bf2f(p[3]);
  }
  *(float4*)(out + i4) = s;
}

// ------------------------- conversion kernels ------------------------------

__global__ void k_convx(const float* __restrict__ x, u16* __restrict__ xb)
{
  const int i = blockIdx.x * blockDim.x + threadIdx.x;
  float4 v = *(const float4*)(x + (size_t)i * 4);
  us4 o; o[0] = f2bf(v.x); o[1] = f2bf(v.y); o[2] = f2bf(v.z); o[3] = f2bf(v.w);
  *(us4*)(xb + (size_t)i * 4) = o;
}

// WT[p][h][e][d] (bf16) = W{q,k,v}[h][d][e] transposed; z = p*8+h over 24
__global__ void k_transpose_qkv(const float* __restrict__ Wq,
                                const float* __restrict__ Wk,
                                const float* __restrict__ Wv,
                                u16* __restrict__ WT)
{
  __shared__ float tile[32][33];
  const int z = blockIdx.z, p = z >> 3, h = z & 7;
  const float* ip = (p == 0 ? Wq : p == 1 ? Wk : Wv) + (size_t)h * 512 * 512;
  u16* op = WT + (size_t)z * 512 * 512;
  const int c0 = blockIdx.x * 32, r0 = blockIdx.y * 32;
  const int tx = threadIdx.x, ty = threadIdx.y;
#pragma unroll
  for (int m = 0; m < 4; m++)
    tile[ty + m * 8][tx] = ip[(size_t)(r0 + ty + m * 8) * 512 + c0 + tx];
  __syncthreads();
#pragma unroll
  for (int m = 0; m < 4; m++)
    op[(size_t)(c0 + ty + m * 8) * 512 + r0 + tx] = f2bf(tile[tx][ty + m * 8]);
}

// out[c][r] (bf16) = in[r][c] (f32)  — for Wo
__global__ void k_transpose_f2b(const float* __restrict__ in, u16* __restrict__ out,
                                int rows, int cols)
{
  __shared__ float tile[32][33];
  const int c0 = blockIdx.x * 32, r0 = blockIdx.y * 32;
  const int tx = threadIdx.x, ty = threadIdx.y;
#pragma unroll
  for (int m = 0; m < 4; m++)
    tile[ty + m * 8][tx] = in[(size_t)(r0 + ty + m * 8) * cols + c0 + tx];
  __syncthreads();
#pragma unroll
  for (int m = 0; m < 4; m++)
    out[(size_t)(c0 + ty + m * 8) * rows + r0 + tx] = f2bf(tile[tx][ty + m * 8]);
}

// ------------------------------ launcher -----------------------------------

extern "C" void kernel_launch(void* const* d_in, const int* in_sizes, int n_in,
                              void* d_out, int out_size, void* d_ws, size_t ws_size,
                              hipStream_t stream)
{
  const float* x  = (const float*)d_in[0];
  const float* Wq = (const float*)d_in[1];
  const float* Wk = (const float*)d_in[2];
  const float* Wv = (const float*)d_in[3];
  const float* bq = (const float*)d_in[4];
  const float* bk = (const float*)d_in[5];
  const float* bv = (const float*)d_in[6];
  const float* Wo = (const float*)d_in[7];
  const float* bo = (const float*)d_in[8];
  float* out = (float*)d_out;

  char* w = (char*)d_ws;
  size_t off = 0;
  auto alloc = [&](size_t bytes) -> char* {
    char* p = w + off; off += (bytes + 255) & ~(size_t)255; return p;
  };
  u16* xb   = (u16*)alloc(4096ull * 512 * 2);          //   4.2 MB
  u16* WT   = (u16*)alloc(3ull * 8 * 512 * 512 * 2);   //  12.6 MB  [p][h][e][d]
  u16* WoT  = (u16*)alloc(512ull * 4096 * 2);          //   4.2 MB  [e][i]
  u16* Q    = (u16*)alloc(16ull * 2048 * 512 * 2);     //  33.6 MB  [bh][s][e]
  u16* Kb   = (u16*)alloc(16ull * 2048 * 512 * 2);     //  33.6 MB  [bh][s][e]
  u16* VT   = (u16*)alloc(16ull * 512 * 2048 * 2);     //  33.6 MB  [bh][e][s]
  u16* conc = (u16*)alloc(4096ull * 4096 * 2);         //  33.6 MB  [b*s][h*e]
  u16* part = (u16*)alloc(4ull * 4096 * 512 * 2);      //  16.8 MB  split-K partials (bf16)
  float* l  = (float*)alloc(16ull * 2048 * 4);         //  128 KB   row sums
  const size_t scoreBytes = 2048ull * 2048 * 2;        //   8.4 MB per bh (bf16)
  int CH = 16;
  while (CH > 1 && off + (size_t)CH * scoreBytes > ws_size) CH >>= 1;
  u16* scores = (u16*)alloc((size_t)CH * scoreBytes);

  // row-sum buffer must start at zero (ws is poisoned before every launch)
  hipMemsetAsync(l, 0, 16ull * 2048 * 4, stream);

  // 1) converts / transposes
  k_convx<<<2048, 256, 0, stream>>>(x, xb);
  dim3 tb(32, 8);
  k_transpose_qkv<<<dim3(16, 16, 24), tb, 0, stream>>>(Wq, Wk, Wv, WT);
  k_transpose_f2b<<<dim3(16, 128, 1), tb, 0, stream>>>(Wo, WoT, 4096, 512);

  // 2) QKV projections
  k_qkv_qk<<<dim3(4, 16, 32), 256, 0, stream>>>(xb, WT, bq, bk, Q, Kb);
  k_qkv_v <<<dim3(4, 16, 16), 256, 0, stream>>>(xb, WT, bv, VT);

  // 3) attention: P_unnorm = exp(QK^T*scale) with fused row sums, then PV/l
  for (int c = 0; c < 16; c += CH){
    k_score<<<dim3(16, 16, CH), 256, 0, stream>>>(Q, Kb, scores, l, c);
    k_pv   <<<dim3(4, 16, CH), 256, 0, stream>>>(scores, VT, l, conc, c);
  }

  // 4) output projection (split-K=4, bf16 partials) + reduce(+bias+residual)
  k_final_sk<<<dim3(4, 32, 4), 256, 0, stream>>>(conc, WoT, part);
  k_reduce<<<2048, 256, 0, stream>>>(part, bo, x, out);
}

// Round 5
// 463.824 us; speedup vs baseline: 1.4160x; 1.0038x over previous
//
#include <hip/hip_runtime.h>

typedef unsigned short u16;
typedef __attribute__((ext_vector_type(8))) short bh8;     // 8 bf16 (4 VGPRs) MFMA operand
typedef __attribute__((ext_vector_type(4))) float f32x4;   // MFMA accumulator
typedef __attribute__((ext_vector_type(4))) u16 us4;

__device__ __forceinline__ u16 f2bf(float f){
  unsigned u = __builtin_bit_cast(unsigned, f);
  u += 0x7fffu + ((u >> 16) & 1u);           // RNE
  return (u16)(u >> 16);
}

__device__ __forceinline__ void gload16(const void* g, void* l){
  __builtin_amdgcn_global_load_lds((const __attribute__((address_space(1))) unsigned*)g,
                                   (__attribute__((address_space(3))) unsigned*)l, 16, 0, 0);
}

// ---------------------------------------------------------------------------
// Generic 128x128-tile bf16 GEMM core (m97 structure): A [M][K], B^T [N][K],
// BK=32, 256 threads = 4 waves, each wave a 64x64 sub-tile (4x4 frags 16x16x32).
// MODE: 1 = bf16 out (+bias by col); 3 = bf16 exp(v*scale) + row-sum atomics;
//       4 = bf16 v/lraw[row]; 5 = bf16 out (+bias by row);
//       6 = f32 atomicAdd into outF (split-K accumulate).
// ---------------------------------------------------------------------------
template<int MODE>
__device__ __forceinline__ void gemm_core(
    u16* As, u16* Bs,
    const u16* __restrict__ A, int lda,
    const u16* __restrict__ B, int ldb,
    int K, float scale,
    const float* __restrict__ bias,
    float* __restrict__ lsum,          // mode 3: row-sum atomics base
    const float* __restrict__ lraw,    // mode 4: row sums base
    u16* __restrict__ outB, float* __restrict__ outF, int ldo,
    int m0, int n0)
{
  const int t  = threadIdx.x;
  const int ln = t & 63;
  const int wv = t >> 6;
  const int wr = wv >> 1;
  const int wc = wv & 1;

  // staging: thread t loads 16B, rows t>>2, k-slot t&3; two rounds (rows 0-63, 64-127)
  const int rs = t >> 2;
  const int cs = (t & 3) * 8;
  const u16* Ag0 = A + (size_t)(m0 + rs) * lda + cs;
  const u16* Ag1 = Ag0 + (size_t)64 * lda;
  const u16* Bg0 = B + (size_t)(n0 + rs) * ldb + cs;
  const u16* Bg1 = Bg0 + (size_t)64 * ldb;
  // wave-uniform LDS dest bases (HW adds lane*16)
  char* lA0 = (char*)As + wv * 1024;
  char* lA1 = lA0 + 4096;
  char* lB0 = (char*)Bs + wv * 1024;
  char* lB1 = lB0 + 4096;

  f32x4 acc[4][4] = {};

  const int frow = (ln & 15);
  const int fk   = (ln >> 4) * 8;

  for (int k0 = 0; k0 < K; k0 += 32){
    gload16(Ag0 + k0, lA0);
    gload16(Ag1 + k0, lA1);
    gload16(Bg0 + k0, lB0);
    gload16(Bg1 + k0, lB1);
    __syncthreads();   // drains vmcnt before LDS reads
    bh8 a[4], b[4];
#pragma unroll
    for (int i = 0; i < 4; i++)
      a[i] = *(const bh8*)&As[(wr*64 + i*16 + frow)*32 + fk];
#pragma unroll
    for (int j = 0; j < 4; j++)
      b[j] = *(const bh8*)&Bs[(wc*64 + j*16 + frow)*32 + fk];
#pragma unroll
    for (int i = 0; i < 4; i++)
#pragma unroll
      for (int j = 0; j < 4; j++)
        acc[i][j] = __builtin_amdgcn_mfma_f32_16x16x32_bf16(a[i], b[j], acc[i][j], 0, 0, 0);
    __syncthreads();
  }

  // epilogue: C/D layout col = lane&15, row = (lane>>4)*4 + reg (m89-verified)
  const int col0 = ln & 15;
  const int r0   = (ln >> 4) * 4;
#pragma unroll
  for (int i = 0; i < 4; i++){
    const int rowb = m0 + wr*64 + i*16 + r0;
    float rsum[4] = {0.f, 0.f, 0.f, 0.f};
    float il[4];
    if (MODE == 4){
#pragma unroll
      for (int q = 0; q < 4; q++) il[q] = 1.0f / lraw[rowb + q];
    }
#pragma unroll
    for (int j = 0; j < 4; j++){
      const int col = n0 + wc*64 + j*16 + col0;
      f32x4 v = acc[i][j];
      if (MODE == 1){
        const float bb = bias ? bias[col] : 0.f;
#pragma unroll
        for (int q = 0; q < 4; q++)
          outB[(size_t)(rowb + q) * ldo + col] = f2bf(v[q] * scale + bb);
      } else if (MODE == 3){
#pragma unroll
        for (int q = 0; q < 4; q++){
          float e = __expf(v[q] * scale);
          rsum[q] += e;
          outB[(size_t)(rowb + q) * ldo + col] = f2bf(e);
        }
      } else if (MODE == 4){
#pragma unroll
        for (int q = 0; q < 4; q++)
          outB[(size_t)(rowb + q) * ldo + col] = f2bf(v[q] * il[q]);
      } else if (MODE == 5){
#pragma unroll
        for (int q = 0; q < 4; q++)
          outB[(size_t)(rowb + q) * ldo + col] = f2bf(v[q] * scale + bias[rowb + q]);
      } else { // 6
#pragma unroll
        for (int q = 0; q < 4; q++)
          atomicAdd(&outF[(size_t)(rowb + q) * ldo + col], v[q]);
      }
    }
    if (MODE == 3){
      // reduce over the 16 col-lanes (xor 1,2,4,8), then 1 atomic per row
#pragma unroll
      for (int q = 0; q < 4; q++){
        float s = rsum[q];
        s += __shfl_xor(s, 1);
        s += __shfl_xor(s, 2);
        s += __shfl_xor(s, 4);
        s += __shfl_xor(s, 8);
        if ((ln & 15) == 0) atomicAdd(&lsum[rowb + q], s);
      }
    }
  }
}

// ---------------------------- prep (fused) ---------------------------------
// blocks [0,2048): xb = bf16(x)
// blocks [2048,8192): WT[p][h][e][d] = transpose(W{q,k,v}[h])
// blocks [8192,10240): WoT[e][i] = transpose(Wo)
// blocks [10240,12288): out = x + bo      (residual+bias pre-init)
// blocks [12288,12416): l = 0
__global__ __launch_bounds__(256) void k_prep(
    const float* __restrict__ x,
    const float* __restrict__ Wq, const float* __restrict__ Wk,
    const float* __restrict__ Wv, const float* __restrict__ Wo,
    const float* __restrict__ bo,
    u16* __restrict__ xb, u16* __restrict__ WT, u16* __restrict__ WoT,
    float* __restrict__ l, float* __restrict__ out)
{
  __shared__ float tile[32][33];
  int bid = blockIdx.x;
  const int t = threadIdx.x;
  if (bid < 2048){
    const size_t i4 = ((size_t)bid * 256 + t) * 4;
    float4 v = *(const float4*)(x + i4);
    us4 o; o[0] = f2bf(v.x); o[1] = f2bf(v.y); o[2] = f2bf(v.z); o[3] = f2bf(v.w);
    *(us4*)(xb + i4) = o;
    return;
  }
  bid -= 2048;
  if (bid < 6144){
    const int z = bid >> 8, tid = bid & 255;
    const int bx = tid & 15, by = tid >> 4;
    const int p = z >> 3, h = z & 7;
    const float* ip = (p == 0 ? Wq : p == 1 ? Wk : Wv) + (size_t)h * 512 * 512;
    u16* op = WT + (size_t)z * 512 * 512;
    const int tx = t & 31, ty = t >> 5;
    const int c0 = bx * 32, r0 = by * 32;
#pragma unroll
    for (int m = 0; m < 4; m++)
      tile[ty + m * 8][tx] = ip[(size_t)(r0 + ty + m * 8) * 512 + c0 + tx];
    __syncthreads();
#pragma unroll
    for (int m = 0; m < 4; m++)
      op[(size_t)(c0 + ty + m * 8) * 512 + r0 + tx] = f2bf(tile[tx][ty + m * 8]);
    return;
  }
  bid -= 6144;
  if (bid < 2048){
    const int bx = bid & 15, by = bid >> 4;     // col tile (512), row tile (4096)
    const int tx = t & 31, ty = t >> 5;
    const int c0 = bx * 32, r0 = by * 32;
#pragma unroll
    for (int m = 0; m < 4; m++)
      tile[ty + m * 8][tx] = Wo[(size_t)(r0 + ty + m * 8) * 512 + c0 + tx];
    __syncthreads();
#pragma unroll
    for (int m = 0; m < 4; m++)
      WoT[(size_t)(c0 + ty + m * 8) * 4096 + r0 + tx] = f2bf(tile[tx][ty + m * 8]);
    return;
  }
  bid -= 2048;
  if (bid < 2048){
    const size_t i4 = ((size_t)bid * 256 + t) * 4;
    const int col = (int)(i4 & 511);
    float4 v = *(const float4*)(x + i4);
    v.x += bo[col]; v.y += bo[col + 1]; v.z += bo[col + 2]; v.w += bo[col + 3];
    *(float4*)(out + i4) = v;
    return;
  }
  bid -= 2048;
  {
    const int i = bid * 256 + t;
    if (i < 32768) l[i] = 0.f;
  }
}

// ---------------------------- QKV (fused) ----------------------------------
// z = p*16 + bh; p=0: Q, p=1: K (row-major [s][e]); p=2: VT[e][s] via
// operand swap (A = WvT[e][d], B = xb[s][d]) with row-indexed bias.
__global__ __launch_bounds__(256) void k_qkv(
    const u16* __restrict__ xb, const u16* __restrict__ WT,
    const float* __restrict__ bq, const float* __restrict__ bk,
    const float* __restrict__ bv,
    u16* __restrict__ Q, u16* __restrict__ Kb, u16* __restrict__ VT)
{
  __shared__ u16 As[4096], Bs[4096];
  const int z = blockIdx.z;
  const int p = z >> 4, bh = z & 15, b = bh >> 3, h = bh & 7;
  if (p < 2){
    const u16* A = xb + (size_t)b * 2048 * 512;
    const u16* B = WT + (size_t)(p * 8 + h) * 512 * 512;
    const float* bias = (p == 0 ? bq : bk) + h * 512;
    u16* o = (p == 0 ? Q : Kb) + (size_t)bh * 2048 * 512;
    gemm_core<1>(As, Bs, A, 512, B, 512, 512, 1.f, bias, nullptr, nullptr,
                 o, nullptr, 512, blockIdx.y * 128, blockIdx.x * 128);
  } else {
    const int tid = blockIdx.y * 4 + blockIdx.x;   // 0..63
    const int m0 = (tid >> 4) * 128;               // e-tile (512)
    const int n0 = (tid & 15) * 128;               // s-tile (2048)
    gemm_core<5>(As, Bs, WT + (size_t)(16 + h) * 512 * 512, 512,
                 xb + (size_t)b * 2048 * 512, 512, 512, 1.f, bv + h * 512,
                 nullptr, nullptr, VT + (size_t)bh * 512 * 2048, nullptr, 2048,
                 m0, n0);
  }
}

// P_unnorm = exp(scale * Q K^T) -> bf16, plus row-sum atomics into l
__global__ __launch_bounds__(256) void k_score(
    const u16* __restrict__ Q, const u16* __restrict__ Kb,
    u16* __restrict__ scoresB, float* __restrict__ l, int bh0)
{
  __shared__ u16 As[4096], Bs[4096];
  const int z = blockIdx.z, bh = bh0 + z;
  gemm_core<3>(As, Bs, Q + (size_t)bh * 2048 * 512, 512,
               Kb + (size_t)bh * 2048 * 512, 512, 512,
               0.044194173824159216f /* 1/sqrt(512) */, nullptr,
               l + (size_t)bh * 2048, nullptr,
               scoresB + (size_t)z * 2048 * 2048, nullptr, 2048,
               blockIdx.y * 128, blockIdx.x * 128);
}

// heads = (P_unnorm V) / l, written into concat[b][s][h*512+e] (bf16)
__global__ __launch_bounds__(256) void k_pv(
    const u16* __restrict__ scoresB, const u16* __restrict__ VT,
    const float* __restrict__ l, u16* __restrict__ concat, int bh0)
{
  __shared__ u16 As[4096], Bs[4096];
  const int z = blockIdx.z, bh = bh0 + z, b = bh >> 3, h = bh & 7;
  gemm_core<4>(As, Bs, scoresB + (size_t)z * 2048 * 2048, 2048,
               VT + (size_t)bh * 512 * 2048, 2048, 2048, 1.f, nullptr,
               nullptr, l + (size_t)bh * 2048,
               concat + (size_t)b * 2048 * 4096 + h * 512, nullptr, 4096,
               blockIdx.y * 128, blockIdx.x * 128);
}

// out += concat @ WoT^T (split-K=4, f32 atomics into pre-initialized out)
__global__ __launch_bounds__(256) void k_final(
    const u16* __restrict__ concat, const u16* __restrict__ WoT,
    float* __restrict__ out)
{
  __shared__ u16 As[4096], Bs[4096];
  const int sk = blockIdx.z;
  gemm_core<6>(As, Bs, concat + sk * 1024, 4096,
               WoT + sk * 1024, 4096, 1024, 1.f, nullptr, nullptr, nullptr,
               nullptr, out, 512, blockIdx.y * 128, blockIdx.x * 128);
}

// ------------------------------ launcher -----------------------------------

extern "C" void kernel_launch(void* const* d_in, const int* in_sizes, int n_in,
                              void* d_out, int out_size, void* d_ws, size_t ws_size,
                              hipStream_t stream)
{
  const float* x  = (const float*)d_in[0];
  const float* Wq = (const float*)d_in[1];
  const float* Wk = (const float*)d_in[2];
  const float* Wv = (const float*)d_in[3];
  const float* bq = (const float*)d_in[4];
  const float* bk = (const float*)d_in[5];
  const float* bv = (const float*)d_in[6];
  const float* Wo = (const float*)d_in[7];
  const float* bo = (const float*)d_in[8];
  float* out = (float*)d_out;

  char* w = (char*)d_ws;
  size_t off = 0;
  auto alloc = [&](size_t bytes) -> char* {
    char* p = w + off; off += (bytes + 255) & ~(size_t)255; return p;
  };
  u16* xb   = (u16*)alloc(4096ull * 512 * 2);          //   4.2 MB
  u16* WT   = (u16*)alloc(3ull * 8 * 512 * 512 * 2);   //  12.6 MB  [p][h][e][d]
  u16* WoT  = (u16*)alloc(512ull * 4096 * 2);          //   4.2 MB  [e][i]
  u16* Q    = (u16*)alloc(16ull * 2048 * 512 * 2);     //  33.6 MB  [bh][s][e]
  u16* Kb   = (u16*)alloc(16ull * 2048 * 512 * 2);     //  33.6 MB  [bh][s][e]
  u16* VT   = (u16*)alloc(16ull * 512 * 2048 * 2);     //  33.6 MB  [bh][e][s]
  u16* conc = (u16*)alloc(4096ull * 4096 * 2);         //  33.6 MB  [b*s][h*e]
  float* l  = (float*)alloc(16ull * 2048 * 4);         //  128 KB   row sums
  const size_t scoreBytes = 2048ull * 2048 * 2;        //   8.4 MB per bh (bf16)
  int CH = 16;
  while (CH > 1 && off + (size_t)CH * scoreBytes > ws_size) CH >>= 1;
  u16* scores = (u16*)alloc((size_t)CH * scoreBytes);

  // 1) fused prep: xb, WT, WoT, out = x + bo, l = 0
  k_prep<<<12416, 256, 0, stream>>>(x, Wq, Wk, Wv, Wo, bo, xb, WT, WoT, l, out);

  // 2) fused QKV projections (Q, K row-major; VT built transposed, coalesced)
  k_qkv<<<dim3(4, 16, 48), 256, 0, stream>>>(xb, WT, bq, bk, bv, Q, Kb, VT);

  // 3) attention: P_unnorm = exp(QK^T*scale) with fused row sums, then PV/l
  for (int c = 0; c < 16; c += CH){
    k_score<<<dim3(16, 16, CH), 256, 0, stream>>>(Q, Kb, scores, l, c);
    k_pv   <<<dim3(4, 16, CH), 256, 0, stream>>>(scores, VT, l, conc, c);
  }

  // 4) output projection: split-K=4 atomic f32 accumulate into out (= x + bo)
  k_final<<<dim3(4, 32, 4), 256, 0, stream>>>(conc, WoT, out);
}

// Round 8
// 441.969 us; speedup vs baseline: 1.4860x; 1.0494x over previous
//
#include <hip/hip_runtime.h>

typedef unsigned short u16;
typedef __attribute__((ext_vector_type(8))) short bh8;     // 8 bf16 (4 VGPRs) MFMA operand
typedef __attribute__((ext_vector_type(4))) float f32x4;   // MFMA accumulator
typedef __attribute__((ext_vector_type(4))) u16 us4;

__device__ __forceinline__ u16 f2bf(float f){
  unsigned u = __builtin_bit_cast(unsigned, f);
  u += 0x7fffu + ((u >> 16) & 1u);           // RNE
  return (u16)(u >> 16);
}
__device__ __forceinline__ float bf2f(u16 b){
  unsigned u = ((unsigned)b) << 16;
  return __builtin_bit_cast(float, u);
}

__device__ __forceinline__ void gload16(const void* g, void* l){
  __builtin_amdgcn_global_load_lds((const __attribute__((address_space(1))) unsigned*)g,
                                   (__attribute__((address_space(3))) unsigned*)l, 16, 0, 0);
}

// ---------------------------------------------------------------------------
// Generic 128x128-tile bf16 GEMM core (m97 structure): A [M][K], B^T [N][K],
// BK=32, 256 threads = 4 waves, each wave a 64x64 sub-tile (4x4 frags 16x16x32).
// MODE: 1 = bf16 out (+bias by col); 3 = bf16 exp(v*scale) + row-sum atomics;
//       4 = bf16 v/lraw[row]; 5 = bf16 out (+bias by row).
// ---------------------------------------------------------------------------
template<int MODE>
__device__ __forceinline__ void gemm_core(
    u16* As, u16* Bs,
    const u16* __restrict__ A, int lda,
    const u16* __restrict__ B, int ldb,
    int K, float scale,
    const float* __restrict__ bias,
    float* __restrict__ lsum,          // mode 3: row-sum atomics base
    const float* __restrict__ lraw,    // mode 4: row sums base
    u16* __restrict__ outB, int ldo,
    int m0, int n0)
{
  const int t  = threadIdx.x;
  const int ln = t & 63;
  const int wv = t >> 6;
  const int wr = wv >> 1;
  const int wc = wv & 1;

  // staging: thread t loads 16B, rows t>>2, k-slot t&3; two rounds (rows 0-63, 64-127)
  const int rs = t >> 2;
  const int cs = (t & 3) * 8;
  const u16* Ag0 = A + (size_t)(m0 + rs) * lda + cs;
  const u16* Ag1 = Ag0 + (size_t)64 * lda;
  const u16* Bg0 = B + (size_t)(n0 + rs) * ldb + cs;
  const u16* Bg1 = Bg0 + (size_t)64 * ldb;
  // wave-uniform LDS dest bases (HW adds lane*16)
  char* lA0 = (char*)As + wv * 1024;
  char* lA1 = lA0 + 4096;
  char* lB0 = (char*)Bs + wv * 1024;
  char* lB1 = lB0 + 4096;

  f32x4 acc[4][4] = {};

  const int frow = (ln & 15);
  const int fk   = (ln >> 4) * 8;

  for (int k0 = 0; k0 < K; k0 += 32){
    gload16(Ag0 + k0, lA0);
    gload16(Ag1 + k0, lA1);
    gload16(Bg0 + k0, lB0);
    gload16(Bg1 + k0, lB1);
    __syncthreads();   // drains vmcnt before LDS reads
    bh8 a[4], b[4];
#pragma unroll
    for (int i = 0; i < 4; i++)
      a[i] = *(const bh8*)&As[(wr*64 + i*16 + frow)*32 + fk];
#pragma unroll
    for (int j = 0; j < 4; j++)
      b[j] = *(const bh8*)&Bs[(wc*64 + j*16 + frow)*32 + fk];
#pragma unroll
    for (int i = 0; i < 4; i++)
#pragma unroll
      for (int j = 0; j < 4; j++)
        acc[i][j] = __builtin_amdgcn_mfma_f32_16x16x32_bf16(a[i], b[j], acc[i][j], 0, 0, 0);
    __syncthreads();
  }

  // epilogue: C/D layout col = lane&15, row = (lane>>4)*4 + reg (m89-verified)
  const int col0 = ln & 15;
  const int r0   = (ln >> 4) * 4;
#pragma unroll
  for (int i = 0; i < 4; i++){
    const int rowb = m0 + wr*64 + i*16 + r0;
    float rsum[4] = {0.f, 0.f, 0.f, 0.f};
    float il[4];
    if (MODE == 4){
#pragma unroll
      for (int q = 0; q < 4; q++) il[q] = 1.0f / lraw[rowb + q];
    }
#pragma unroll
    for (int j = 0; j < 4; j++){
      const int col = n0 + wc*64 + j*16 + col0;
      f32x4 v = acc[i][j];
      if (MODE == 1){
        const float bb = bias ? bias[col] : 0.f;
#pragma unroll
        for (int q = 0; q < 4; q++)
          outB[(size_t)(rowb + q) * ldo + col] = f2bf(v[q] * scale + bb);
      } else if (MODE == 3){
#pragma unroll
        for (int q = 0; q < 4; q++){
          float e = __expf(v[q] * scale);
          rsum[q] += e;
          outB[(size_t)(rowb + q) * ldo + col] = f2bf(e);
        }
      } else if (MODE == 4){
#pragma unroll
        for (int q = 0; q < 4; q++)
          outB[(size_t)(rowb + q) * ldo + col] = f2bf(v[q] * il[q]);
      } else { // 5
#pragma unroll
        for (int q = 0; q < 4; q++)
          outB[(size_t)(rowb + q) * ldo + col] = f2bf(v[q] * scale + bias[rowb + q]);
      }
    }
    if (MODE == 3){
      // reduce over the 16 col-lanes (xor 1,2,4,8), then 1 atomic per row
#pragma unroll
      for (int q = 0; q < 4; q++){
        float s = rsum[q];
        s += __shfl_xor(s, 1);
        s += __shfl_xor(s, 2);
        s += __shfl_xor(s, 4);
        s += __shfl_xor(s, 8);
        if ((ln & 15) == 0) atomicAdd(&lsum[rowb + q], s);
      }
    }
  }
}

// ---------------------------- prep (fused) ---------------------------------
// blocks [0,2048): xb = bf16(x)
// blocks [2048,8192): WT[p][h][e][d] = transpose(W{q,k,v}[h])
// blocks [8192,10240): WoT[e][i] = transpose(Wo)
// blocks [10240,10368): l = 0
__global__ __launch_bounds__(256) void k_prep(
    const float* __restrict__ x,
    const float* __restrict__ Wq, const float* __restrict__ Wk,
    const float* __restrict__ Wv, const float* __restrict__ Wo,
    u16* __restrict__ xb, u16* __restrict__ WT, u16* __restrict__ WoT,
    float* __restrict__ l)
{
  __shared__ float tile[32][33];
  int bid = blockIdx.x;
  const int t = threadIdx.x;
  if (bid < 2048){
    const size_t i4 = ((size_t)bid * 256 + t) * 4;
    float4 v = *(const float4*)(x + i4);
    us4 o; o[0] = f2bf(v.x); o[1] = f2bf(v.y); o[2] = f2bf(v.z); o[3] = f2bf(v.w);
    *(us4*)(xb + i4) = o;
    return;
  }
  bid -= 2048;
  if (bid < 6144){
    const int z = bid >> 8, tid = bid & 255;
    const int bx = tid & 15, by = tid >> 4;
    const int p = z >> 3, h = z & 7;
    const float* ip = (p == 0 ? Wq : p == 1 ? Wk : Wv) + (size_t)h * 512 * 512;
    u16* op = WT + (size_t)z * 512 * 512;
    const int tx = t & 31, ty = t >> 5;
    const int c0 = bx * 32, r0 = by * 32;
#pragma unroll
    for (int m = 0; m < 4; m++)
      tile[ty + m * 8][tx] = ip[(size_t)(r0 + ty + m * 8) * 512 + c0 + tx];
    __syncthreads();
#pragma unroll
    for (int m = 0; m < 4; m++)
      op[(size_t)(c0 + ty + m * 8) * 512 + r0 + tx] = f2bf(tile[tx][ty + m * 8]);
    return;
  }
  bid -= 6144;
  if (bid < 2048){
    const int bx = bid & 15, by = bid >> 4;     // col tile (512), row tile (4096)
    const int tx = t & 31, ty = t >> 5;
    const int c0 = bx * 32, r0 = by * 32;
#pragma unroll
    for (int m = 0; m < 4; m++)
      tile[ty + m * 8][tx] = Wo[(size_t)(r0 + ty + m * 8) * 512 + c0 + tx];
    __syncthreads();
#pragma unroll
    for (int m = 0; m < 4; m++)
      WoT[(size_t)(c0 + ty + m * 8) * 4096 + r0 + tx] = f2bf(tile[tx][ty + m * 8]);
    return;
  }
  bid -= 2048;
  {
    const int i = bid * 256 + t;
    if (i < 32768) l[i] = 0.f;
  }
}

// ---------------------------- QKV (fused) ----------------------------------
// z = p*16 + bh; p=0: Q, p=1: K (row-major [s][e]); p=2: VT[e][s] via
// operand swap (A = WvT[e][d], B = xb[s][d]) with row-indexed bias.
__global__ __launch_bounds__(256) void k_qkv(
    const u16* __restrict__ xb, const u16* __restrict__ WT,
    const float* __restrict__ bq, const float* __restrict__ bk,
    const float* __restrict__ bv,
    u16* __restrict__ Q, u16* __restrict__ Kb, u16* __restrict__ VT)
{
  __shared__ u16 As[4096], Bs[4096];
  const int z = blockIdx.z;
  const int p = z >> 4, bh = z & 15, b = bh >> 3, h = bh & 7;
  if (p < 2){
    const u16* A = xb + (size_t)b * 2048 * 512;
    const u16* B = WT + (size_t)(p * 8 + h) * 512 * 512;
    const float* bias = (p == 0 ? bq : bk) + h * 512;
    u16* o = (p == 0 ? Q : Kb) + (size_t)bh * 2048 * 512;
    gemm_core<1>(As, Bs, A, 512, B, 512, 512, 1.f, bias, nullptr, nullptr,
                 o, 512, blockIdx.y * 128, blockIdx.x * 128);
  } else {
    const int tid = blockIdx.y * 4 + blockIdx.x;   // 0..63
    const int m0 = (tid >> 4) * 128;               // e-tile (512)
    const int n0 = (tid & 15) * 128;               // s-tile (2048)
    gemm_core<5>(As, Bs, WT + (size_t)(16 + h) * 512 * 512, 512,
                 xb + (size_t)b * 2048 * 512, 512, 512, 1.f, bv + h * 512,
                 nullptr, nullptr, VT + (size_t)bh * 512 * 2048, 2048,
                 m0, n0);
  }
}

// P_unnorm = exp(scale * Q K^T) -> bf16, plus row-sum atomics into l
__global__ __launch_bounds__(256) void k_score(
    const u16* __restrict__ Q, const u16* __restrict__ Kb,
    u16* __restrict__ scoresB, float* __restrict__ l, int bh0)
{
  __shared__ u16 As[4096], Bs[4096];
  const int z = blockIdx.z, bh = bh0 + z;
  gemm_core<3>(As, Bs, Q + (size_t)bh * 2048 * 512, 512,
               Kb + (size_t)bh * 2048 * 512, 512, 512,
               0.044194173824159216f /* 1/sqrt(512) */, nullptr,
               l + (size_t)bh * 2048, nullptr,
               scoresB + (size_t)z * 2048 * 2048, 2048,
               blockIdx.y * 128, blockIdx.x * 128);
}

// heads = (P_unnorm V) / l, written into concat[b][s][h*512+e] (bf16)
__global__ __launch_bounds__(256) void k_pv(
    const u16* __restrict__ scoresB, const u16* __restrict__ VT,
    const float* __restrict__ l, u16* __restrict__ concat, int bh0)
{
  __shared__ u16 As[4096], Bs[4096];
  const int z = blockIdx.z, bh = bh0 + z, b = bh >> 3, h = bh & 7;
  gemm_core<4>(As, Bs, scoresB + (size_t)z * 2048 * 2048, 2048,
               VT + (size_t)bh * 512 * 2048, 2048, 2048, 1.f, nullptr,
               nullptr, l + (size_t)bh * 2048,
               concat + (size_t)b * 2048 * 4096 + h * 512, 4096,
               blockIdx.y * 128, blockIdx.x * 128);
}

// out-proj partials (bf16): partial[sk] = concat[:, sk*1024:(sk+1)*1024] @ WoT_slice
__global__ __launch_bounds__(256) void k_final_sk(
    const u16* __restrict__ concat, const u16* __restrict__ WoT,
    u16* __restrict__ partialB)
{
  __shared__ u16 As[4096], Bs[4096];
  const int sk = blockIdx.z;
  gemm_core<1>(As, Bs, concat + sk * 1024, 4096,
               WoT + sk * 1024, 4096, 1024, 1.f, nullptr, nullptr, nullptr,
               partialB + (size_t)sk * 4096 * 512, 512,
               blockIdx.y * 128, blockIdx.x * 128);
}

// out = sum_sk partial[sk] + bo + x   (vectorized x4)
__global__ __launch_bounds__(256) void k_reduce(
    const u16* __restrict__ partialB, const float* __restrict__ bo,
    const float* __restrict__ x, float* __restrict__ out)
{
  const size_t i4 = ((size_t)blockIdx.x * 256 + threadIdx.x) * 4;  // 2M elems
  const int col = (int)(i4 & 511);
  float4 s = *(const float4*)(x + i4);
  s.x += bo[col]; s.y += bo[col + 1]; s.z += bo[col + 2]; s.w += bo[col + 3];
#pragma unroll
  for (int sk = 0; sk < 4; sk++){
    us4 p = *(const us4*)(partialB + (size_t)sk * 2097152 + i4);
    s.x += bf2f(p[0]); s.y += bf2f(p[1]); s.z += bf2f(p[2]); s.w += bf2f(p[3]);
  }
  *(float4*)(out + i4) = s;
}

// ------------------------------ launcher -----------------------------------

extern "C" void kernel_launch(void* const* d_in, const int* in_sizes, int n_in,
                              void* d_out, int out_size, void* d_ws, size_t ws_size,
                              hipStream_t stream)
{
  const float* x  = (const float*)d_in[0];
  const float* Wq = (const float*)d_in[1];
  const float* Wk = (const float*)d_in[2];
  const float* Wv = (const float*)d_in[3];
  const float* bq = (const float*)d_in[4];
  const float* bk = (const float*)d_in[5];
  const float* bv = (const float*)d_in[6];
  const float* Wo = (const float*)d_in[7];
  const float* bo = (const float*)d_in[8];
  float* out = (float*)d_out;

  char* w = (char*)d_ws;
  size_t off = 0;
  auto alloc = [&](size_t bytes) -> char* {
    char* p = w + off; off += (bytes + 255) & ~(size_t)255; return p;
  };
  u16* xb   = (u16*)alloc(4096ull * 512 * 2);          //   4.2 MB
  u16* WT   = (u16*)alloc(3ull * 8 * 512 * 512 * 2);   //  12.6 MB  [p][h][e][d]
  u16* WoT  = (u16*)alloc(512ull * 4096 * 2);          //   4.2 MB  [e][i]
  u16* Q    = (u16*)alloc(16ull * 2048 * 512 * 2);     //  33.6 MB  [bh][s][e]
  u16* Kb   = (u16*)alloc(16ull * 2048 * 512 * 2);     //  33.6 MB  [bh][s][e]
  u16* VT   = (u16*)alloc(16ull * 512 * 2048 * 2);     //  33.6 MB  [bh][e][s]
  u16* conc = (u16*)alloc(4096ull * 4096 * 2);         //  33.6 MB  [b*s][h*e]
  u16* part = (u16*)alloc(4ull * 4096 * 512 * 2);      //  16.8 MB  split-K partials (bf16)
  float* l  = (float*)alloc(16ull * 2048 * 4);         //  128 KB   row sums
  const size_t scoreBytes = 2048ull * 2048 * 2;        //   8.4 MB per bh (bf16)
  int CH = 16;
  while (CH > 1 && off + (size_t)CH * scoreBytes > ws_size) CH >>= 1;
  u16* scores = (u16*)alloc((size_t)CH * scoreBytes);

  // 1) fused prep: xb, WT, WoT, l = 0
  k_prep<<<10368, 256, 0, stream>>>(x, Wq, Wk, Wv, Wo, xb, WT, WoT, l);

  // 2) fused QKV projections (Q, K row-major; VT built transposed, coalesced)
  k_qkv<<<dim3(4, 16, 48), 256, 0, stream>>>(xb, WT, bq, bk, bv, Q, Kb, VT);

  // 3) attention: P_unnorm = exp(QK^T*scale) with fused row sums, then PV/l
  for (int c = 0; c < 16; c += CH){
    k_score<<<dim3(16, 16, CH), 256, 0, stream>>>(Q, Kb, scores, l, c);
    k_pv   <<<dim3(4, 16, CH), 256, 0, stream>>>(scores, VT, l, conc, c);
  }

  // 4) output projection (split-K=4, bf16 partials) + reduce(+bias+residual)
  k_final_sk<<<dim3(4, 32, 4), 256, 0, stream>>>(conc, WoT, part);
  k_reduce<<<2048, 256, 0, stream>>>(part, bo, x, out);
}